// Round 6
// baseline (30.522 us; speedup 1.0000x reference)
//
#include <hip/hip_runtime.h>

typedef float f4 __attribute__((ext_vector_type(4)));
typedef float f32x4 __attribute__((ext_vector_type(4)));
typedef short s16x8 __attribute__((ext_vector_type(8)));
typedef short s16x4 __attribute__((ext_vector_type(4)));

// MoA gate as MFMA GEMM: [32768 tok x 1024 d] x [1024 d x 9 experts(pad 16)].
// Block = 256 thr (4 waves); each wave owns a 16-token tile, streams K in 8
// steps of 128 into its PRIVATE 4KB LDS buffer (no inter-wave sync in the
// main loop). W staged once/block as bf16 in MFMA-B layout (32KB, one
// syncthreads). mfma_f32_16x16x32_bf16 does the k-reduction; epilogue does
// the 3x3 double-softmax on 16 lanes via a tiny LDS roundtrip.
// Layout per 32-k chunk (1KB): cell byte = (g*16 + row)*16 + e*2, so both
// ds_write_b128 (staging) and ds_read_b128 at lane*16 (frags) are even
// across banks (minimum-time, no conflicts).

#define WPB 4       // waves per block
#define TPT 16      // tokens per tile = MFMA M

__device__ __forceinline__ unsigned short f2bf(float x) {  // RNE fp32->bf16
  unsigned u = __float_as_uint(x);
  unsigned r = u + 0x7FFF + ((u >> 16) & 1);
  return (unsigned short)(r >> 16);
}

__global__ __launch_bounds__(256)
void moa_mfma(const float* __restrict__ tok,
              const float* __restrict__ Wq,
              const float* __restrict__ Wk,
              const float* __restrict__ Wv,
              float* __restrict__ out) {
  __shared__ __align__(16) unsigned char lds[32768 + WPB * 4096];
  unsigned char* const ldsW = lds;
  const int tid = threadIdx.x;

  // ---- stage W once per block: zero-fill (pad experts 9..15), then fill ----
#pragma unroll
  for (int z = 0; z < 8; ++z)
    *(f4*)(ldsW + tid * 128 + z * 16) = (f4)0.0f;           // 256*128 = 32KB
  __syncthreads();
  {
    const float* Wsrc[3] = {Wq, Wk, Wv};
    const int k0 = tid * 4;                                  // k 0..1023 by 4
    const int kc = k0 >> 5, j = k0 & 31, g = j >> 3, e2 = j & 7;
#pragma unroll
    for (int m = 0; m < 3; ++m)
#pragma unroll
      for (int e = 0; e < 3; ++e) {
        const int n = m * 3 + e;                             // expert col 0..8
        f4 wv = *(const f4*)(Wsrc[m] + e * 1024 + k0);
        s16x4 hv;
        hv[0] = (short)f2bf(wv.x); hv[1] = (short)f2bf(wv.y);
        hv[2] = (short)f2bf(wv.z); hv[3] = (short)f2bf(wv.w);
        *(s16x4*)(ldsW + kc * 1024 + (g * 16 + n) * 16 + e2 * 2) = hv;
      }
  }
  __syncthreads();

  // ---- per-wave 16-token tile ----
  const int wid = tid >> 6, lane = tid & 63;
  const int T0 = (blockIdx.x * WPB + wid) * TPT;
  const int m = lane >> 2, q4 = lane & 3;                    // token row, k-quarter
  unsigned char* const ldsX = lds + 32768 + wid * 4096;
  const float* gbase = tok + (size_t)(T0 + m) * 1024 + q4 * 32;

  f32x4 acc = (f32x4)0.0f;
  f4 stA[8], stB[8];
#pragma unroll
  for (int g2 = 0; g2 < 8; ++g2) stA[g2] = *(const f4*)(gbase + g2 * 4);

#pragma unroll
  for (int s = 0; s < 8; ++s) {
    f4* cur = (s & 1) ? stB : stA;                           // compile-time after unroll
    f4* nxt = (s & 1) ? stA : stB;
    if (s < 7) {                                             // prefetch next K-step
#pragma unroll
      for (int g2 = 0; g2 < 8; ++g2)
        nxt[g2] = *(const f4*)(gbase + (s + 1) * 128 + g2 * 4);
    }
    // pack this lane's 32 floats (k = s*128 + q4*32 + [0,32)) into chunk q4
#pragma unroll
    for (int g = 0; g < 4; ++g) {
      s16x8 h;
#pragma unroll
      for (int e = 0; e < 8; ++e)
        h[e] = (short)f2bf(cur[g * 2 + (e >> 2)][e & 3]);
      *(s16x8*)(ldsX + q4 * 1024 + (g * 16 + m) * 16) = h;
    }
    // 4 MFMAs consume the 4 chunks (k-accumulate into the SAME acc)
#pragma unroll
    for (int kc = 0; kc < 4; ++kc) {
      s16x8 a = *(s16x8*)(ldsX + kc * 1024 + lane * 16);
      s16x8 b = *(s16x8*)(ldsW + (s * 4 + kc) * 1024 + lane * 16);
      acc = __builtin_amdgcn_mfma_f32_16x16x32_bf16(a, b, acc, 0, 0, 0);
    }
  }

  // ---- epilogue: C[row=4*(lane>>4)+i][col=lane&15] -> LDS -> softmax ----
  float* cbuf = (float*)ldsX;                                 // wave-private
#pragma unroll
  for (int i = 0; i < 4; ++i) {
    const int row = (lane >> 4) * 4 + i, col = lane & 15;
    cbuf[row * 17 + col] = acc[i];
  }
  asm volatile("s_waitcnt lgkmcnt(0)" ::: "memory");
  if (lane < 16) {
    float r[9];
#pragma unroll
    for (int c = 0; c < 9; ++c) r[c] = cbuf[lane * 17 + c];
    // q=r[0..2], k=r[3..5], v=r[6..8]
    float lg[3];
#pragma unroll
    for (int e = 0; e < 3; ++e) {
      float e0 = __expf(r[e] * r[3]);
      float e1 = __expf(r[e] * r[4]);
      float e2 = __expf(r[e] * r[5]);
      float den = (e0 + e1) + e2;
      float num = e0 * r[6] + e1 * r[7] + e2 * r[8];
      lg[e] = num * __builtin_amdgcn_rcpf(den);
    }
    float u0 = __expf(lg[0]);
    float u1 = __expf(lg[1]);
    float u2 = __expf(lg[2]);
    float rs = __builtin_amdgcn_rcpf((u0 + u1) + u2);
    const size_t T = (size_t)T0 + lane;
    out[T * 3 + 0] = u0 * rs;
    out[T * 3 + 1] = u1 * rs;
    out[T * 3 + 2] = u2 * rs;
  }
}

extern "C" void kernel_launch(void* const* d_in, const int* in_sizes, int n_in,
                              void* d_out, int out_size, void* d_ws, size_t ws_size,
                              hipStream_t stream) {
  const float* tok = (const float*)d_in[0];
  const float* Wq  = (const float*)d_in[1];
  const float* Wk  = (const float*)d_in[2];
  const float* Wv  = (const float*)d_in[3];
  float* out = (float*)d_out;

  const int n_tokens = in_sizes[0] / 1024;         // 32768
  const int blocks   = n_tokens / (WPB * TPT);     // 512

  hipLaunchKernelGGL(moa_mfma, dim3(blocks), dim3(256), 0, stream,
                     tok, Wq, Wk, Wv, out);
}